// Round 9
// baseline (160.079 us; speedup 1.0000x reference)
//
#include <hip/hip_runtime.h>

// GaussianKernel: out[row, o] = exp(-(||x_row||^2 - 2 x_row.w_o + ||w_o||^2)) + b[o]
// x: 262144 rows x 32 fp32; w: [32,128]; b: [128]; out fp32.
//
// Round-8 post-mortem: all row-broadcast variants wall at ~60 us because
// delivering the shared 128-B x row to 64 lanes costs ~1 KB of register-file
// writes per read (ds_read_b128 broadcast ~12 cyc; 8/row -> ~82 us of DS pipe).
// Fix: transpose the decomposition. Lane = ROW: x row is lane-private in VGPRs
// (loaded once), xsq lane-private. Loop over 128 output columns with the
// SHARED operand w[:,o] in SGPRs (s_load of pre-transposed wT from d_ws;
// scalar-cache-hot 16 KB). Dot = 32 v_fmac(acc, s, v): zero DS, no broadcast.

constexpr int C_DIM   = 32;
constexpr int OUT_DIM = 128;
constexpr int WT_STRIDE = 40;   // {w[0..31], wsq, bias, pad...} -> 160-B rows
constexpr float LOG2E = 1.4426950408889634f;

// --- prep: wT[o] = {w[:,o], ||w[:,o]||^2, b[o]} ---  (1 block, trivial)
__global__ __launch_bounds__(128)
void prep_w_kernel(const float* __restrict__ w, const float* __restrict__ bias,
                   float* __restrict__ wT)
{
    const int o = threadIdx.x;          // 128 threads, one per output column
    float* row = wT + o * WT_STRIDE;
    float s = 0.f;
#pragma unroll
    for (int c = 0; c < C_DIM; ++c) {   // w[c*128+o]: coalesced across threads
        const float v = w[c * OUT_DIM + o];
        row[c] = v;
        s = fmaf(v, v, s);
    }
    row[32] = s;
    row[33] = bias[o];
}

__global__ __launch_bounds__(256, 4)
void gaussian_rbf_kernel(const float* __restrict__ x,
                         const float* __restrict__ wT,
                         float* __restrict__ out,
                         int total_rows)
{
    const long row = (long)blockIdx.x * blockDim.x + threadIdx.x;  // lane = row
    if (row >= total_rows) return;

    // --- lane-private x row -> 32 VGPRs; xsq lane-private (no broadcast ever).
    float xs[C_DIM];
    float xsq = 0.f;
    {
        const float4* xp = reinterpret_cast<const float4*>(x + row * C_DIM);
#pragma unroll
        for (int k = 0; k < 8; ++k) {
            const float4 v = xp[k];
            xs[4*k+0] = v.x; xs[4*k+1] = v.y; xs[4*k+2] = v.z; xs[4*k+3] = v.w;
            xsq = fmaf(v.x, v.x, xsq);
            xsq = fmaf(v.y, v.y, xsq);
            xsq = fmaf(v.z, v.z, xsq);
            xsq = fmaf(v.w, v.w, xsq);
        }
    }

    float* op = out + row * OUT_DIM;

    // --- o-loop: w column + wsq + bias arrive via s_load (uniform address),
    // consumed as the scalar operand of v_fmac. 4 columns per group -> one
    // float4 store per group (64-B L2 lines complete within 4 groups).
    for (int o = 0; o < OUT_DIM; o += 4) {
        float4 res;
#pragma unroll
        for (int oo = 0; oo < 4; ++oo) {
            const float* wr = wT + (o + oo) * WT_STRIDE;   // uniform -> SGPRs
            float d0 = 0.f, d1 = 0.f, d2 = 0.f, d3 = 0.f;
#pragma unroll
            for (int c = 0; c < 8; ++c) {
                d0 = fmaf(xs[c],      wr[c],      d0);
                d1 = fmaf(xs[c + 8],  wr[c + 8],  d1);
                d2 = fmaf(xs[c + 16], wr[c + 16], d2);
                d3 = fmaf(xs[c + 24], wr[c + 24], d3);
            }
            const float d   = (d0 + d1) + (d2 + d3);
            const float sw  = wr[32];                      // wsq (SGPR)
            const float sb  = wr[33];                      // bias (SGPR)
            // exp(-(xsq - 2d + wsq)) = exp2(L*(2d - (xsq+wsq)))
            const float tmp = xsq + sw;
            const float f   = fmaf(d, 2.f, -tmp);
            float r = exp2f(f * LOG2E) + sb;
            (&res.x)[oo] = r;
        }
        *reinterpret_cast<float4*>(op + o) = res;          // 16 B, aligned
    }
}

extern "C" void kernel_launch(void* const* d_in, const int* in_sizes, int n_in,
                              void* d_out, int out_size, void* d_ws, size_t ws_size,
                              hipStream_t stream) {
    const float* x = (const float*)d_in[0];
    const float* w = (const float*)d_in[1];
    const float* b = (const float*)d_in[2];
    float* out = (float*)d_out;
    float* wT  = (float*)d_ws;                 // 128*40*4 = 20 KB scratch

    const int total_rows = in_sizes[0] / C_DIM;            // 262144
    const int nblocks = (total_rows + 255) / 256;          // 1024

    prep_w_kernel<<<1, 128, 0, stream>>>(w, b, wT);
    gaussian_rbf_kernel<<<nblocks, 256, 0, stream>>>(x, wT, out, total_rows);
}

// Round 10
// 33.711 us; speedup vs baseline: 4.7486x; 4.7486x over previous
//
#include <hip/hip_runtime.h>

// GaussianKernel: out[row, o] = exp(-(||x_row||^2 - 2 x_row.w_o + ||w_o||^2)) + b[o]
// x: 262144 rows x 32 fp32; w: [32,128]; b: [128]; out fp32.
//
// Rounds 3-9 post-mortem: every VALU-dot decomposition pays one of
// {x-broadcast pipe cost, cold per-row latency, scattered stores} -> 60 us wall.
// Fix: the dot IS a GEMM [262144x32]x[32x128] -> mfma_f32_16x16x32_bf16 (K=32
// in ONE mfma). bf16 error analysis: diff_norm ~ 2*chi2_32 >= ~8 over 33M pairs
// -> out err = exp(-dn)*0.26 <= 1e-4 << 5.4e-2 threshold. xsq/wsq/bias fp32.
// Each lane loads only its own A fragment (no broadcast); C layout (m89):
// col=lane&15, row=(lane>>4)*4+reg -> 64B-coalesced stores.

typedef short bf16x8 __attribute__((ext_vector_type(8)));
typedef float f32x4  __attribute__((ext_vector_type(4)));

constexpr int C_DIM   = 32;
constexpr int OUT_DIM = 128;
constexpr int ROWTILES_PER_BLOCK = 4;    // 4 x 32 rows = 128 rows per block
constexpr float LOG2E = 1.4426950408889634f;

__device__ __forceinline__ short f2bf(float f) {   // RNE fp32->bf16 (no NaN in data)
    unsigned u = __float_as_uint(f);
    u += 0x7fffu + ((u >> 16) & 1u);
    return (short)(u >> 16);
}

__global__ __launch_bounds__(256, 4)
void gaussian_mfma_kernel(const float* __restrict__ x,
                          const float* __restrict__ w,
                          const float* __restrict__ bias,
                          float* __restrict__ out,
                          int total_rows)
{
    const int lane = threadIdx.x & 63;
    const int wid  = threadIdx.x >> 6;
    const int colHalf = wid & 1;        // wave covers cols [colHalf*64, +64)
    const int rowSub  = wid >> 1;       // which 16-row sub-tile of the 32-row tile
    const int cbase = colHalf * 64;
    const int kg = lane >> 4;           // k-group 0..3 (8 k each)
    const int lr = lane & 15;           // row (A) / col (B,C) within 16-tile

    // --- B fragments for 4 col-tiles + fp32 wsq/bias: once per block ---
    // B[k][col]: lane holds k = kg*8+j, col = cbase + t*16 + lr.
    bf16x8 bfrag[4];
    float  wsqv[4], bv[4];
#pragma unroll
    for (int t = 0; t < 4; ++t) {
        const int col = cbase + t * 16 + lr;
        float tmp[8];
        float p = 0.f;
#pragma unroll
        for (int j = 0; j < 8; ++j) {
            const float v = w[(kg * 8 + j) * OUT_DIM + col];  // 16KB, L1-hot
            tmp[j] = v;
            p = fmaf(v, v, p);
        }
        p += __shfl_xor(p, 16);          // combine the 4 k-groups -> full ||w_col||^2
        p += __shfl_xor(p, 32);
        wsqv[t] = p;
        bv[t]   = bias[col];
#pragma unroll
        for (int j = 0; j < 8; ++j) bfrag[t][j] = f2bf(tmp[j]);
    }

    for (int rt = 0; rt < ROWTILES_PER_BLOCK; ++rt) {
        const long row0 = (long)blockIdx.x * (32 * ROWTILES_PER_BLOCK)
                        + rt * 32 + rowSub * 16;
        if (row0 >= total_rows) break;

        // A fragment: lane holds x[row0+lr][kg*8 .. kg*8+8) -- 2 float4 loads.
        const float4* xp = reinterpret_cast<const float4*>(
            x + (row0 + lr) * C_DIM + kg * 8);
        const float4 a0 = xp[0], a1 = xp[1];

        // fp32 xsq: per-lane partial over its 8 elems, combine across k-groups.
        float p = 0.f;
        p = fmaf(a0.x, a0.x, p); p = fmaf(a0.y, a0.y, p);
        p = fmaf(a0.z, a0.z, p); p = fmaf(a0.w, a0.w, p);
        p = fmaf(a1.x, a1.x, p); p = fmaf(a1.y, a1.y, p);
        p = fmaf(a1.z, a1.z, p); p = fmaf(a1.w, a1.w, p);
        p += __shfl_xor(p, 16);
        p += __shfl_xor(p, 32);          // all lanes: xsq[row0 + lr]

        bf16x8 afrag;
        afrag[0] = f2bf(a0.x); afrag[1] = f2bf(a0.y);
        afrag[2] = f2bf(a0.z); afrag[3] = f2bf(a0.w);
        afrag[4] = f2bf(a1.x); afrag[5] = f2bf(a1.y);
        afrag[6] = f2bf(a1.z); afrag[7] = f2bf(a1.w);

        // xsq values for the 4 C rows this lane writes: row = kg*4 + reg.
        float xq[4];
#pragma unroll
        for (int reg = 0; reg < 4; ++reg)
            xq[reg] = __shfl(p, kg * 4 + reg);   // bpermute; value replicated

        // 4 MFMAs: one per 16-col tile, each with full K=32.
        f32x4 acc[4];
#pragma unroll
        for (int t = 0; t < 4; ++t) {
            acc[t] = (f32x4){0.f, 0.f, 0.f, 0.f};
            acc[t] = __builtin_amdgcn_mfma_f32_16x16x32_bf16(
                         afrag, bfrag[t], acc[t], 0, 0, 0);
        }

        // Epilogue + store. C layout (m89): col = lane&15, row = (lane>>4)*4+reg.
#pragma unroll
        for (int t = 0; t < 4; ++t) {
#pragma unroll
            for (int reg = 0; reg < 4; ++reg) {
                const float d   = acc[t][reg];
                const float arg = (fmaf(2.f, d, -xq[reg]) - wsqv[t]) * LOG2E;
                const float r   = exp2f(arg) + bv[t];
                out[(row0 + kg * 4 + reg) * OUT_DIM + cbase + t * 16 + lr] = r;
            }
        }
    }
}

extern "C" void kernel_launch(void* const* d_in, const int* in_sizes, int n_in,
                              void* d_out, int out_size, void* d_ws, size_t ws_size,
                              hipStream_t stream) {
    const float* x = (const float*)d_in[0];
    const float* w = (const float*)d_in[1];
    const float* b = (const float*)d_in[2];
    float* out = (float*)d_out;

    const int total_rows = in_sizes[0] / C_DIM;                // 262144
    const int rows_per_block = 32 * ROWTILES_PER_BLOCK;        // 128
    const int nblocks = (total_rows + rows_per_block - 1) / rows_per_block;  // 2048

    gaussian_mfma_kernel<<<nblocks, 256, 0, stream>>>(x, w, b, out, total_rows);
}